// Round 3
// baseline (217.499 us; speedup 1.0000x reference)
//
#include <hip/hip_runtime.h>

// Problem constants (fixed by setup_inputs in the reference):
//   pred_dT, gt_dT: (B=32, M=784, M=784, C=4) float32
//   Ms: (V=4,) int32, sum(Ms) == M
constexpr int B_ = 32;
constexpr int M_ = 784;

constexpr int NBLK = 2048;                       // TOTAL / NBLK is exact
constexpr int NTHR = 256;
constexpr int TOTAL = B_ * M_ * M_;              // 19,668,992 float4 pixels
constexpr int PER_BLOCK = TOTAL / NBLK;          // 9604 (exact!)
constexpr int KFULL = PER_BLOCK / NTHR;          // 37 full iterations
constexpr int TAILN = PER_BLOCK - KFULL * NTHR;  // 132-thread tail

constexpr float ALPHA_T  = 0.5f;
constexpr float ALPHA_S  = 0.75f;
constexpr float ALPHA_TS = 0.5f;
constexpr float EPS      = 1e-8f;

__device__ __forceinline__ void final_math(float total_all_t, float total_all_s,
                                           float total_intra_t, float total_intra_s,
                                           const int* __restrict__ Ms,
                                           float* __restrict__ out)
{
    const float total_inter_t = total_all_t - total_intra_t;
    const float total_inter_s = total_all_s - total_intra_s;

    int sum_Ms_sq = 0;
    #pragma unroll
    for (int v = 0; v < 4; ++v) sum_Ms_sq += Ms[v] * Ms[v];
    const float diag_count    = (float)((long long)sum_Ms_sq * B_);
    const float offdiag_count = (float)(((long long)M_ * M_ - sum_Ms_sq) * B_);

    const float li_t = (diag_count    > EPS) ? total_intra_t / diag_count    : 0.f;
    const float le_t = (offdiag_count > EPS) ? total_inter_t / offdiag_count : 0.f;
    const float li_s = (diag_count    > EPS) ? total_intra_s / diag_count    : 0.f;
    const float le_s = (offdiag_count > EPS) ? total_inter_s / offdiag_count : 0.f;

    const float loss_t = ALPHA_T  * le_t + (1.f - ALPHA_T)  * li_t;
    const float loss_s = ALPHA_S  * le_s + (1.f - ALPHA_S)  * li_s;
    const float loss   = ALPHA_TS * loss_t + (1.f - ALPHA_TS) * loss_s;

    out[0] = li_t;
    out[1] = le_t;
    out[2] = li_s;
    out[3] = le_s;
    out[4] = loss_t;
    out[5] = loss_s;
    out[6] = loss;
}

// ---------------------------------------------------------------------------
// Fused kernel: exact-chunked contiguous work per block (perfect balance),
// last-block-done final reduction (deterministic: fixed-order sum by one
// block). counter is zeroed by a hipMemsetAsync before each launch.
// ---------------------------------------------------------------------------
__global__ __launch_bounds__(NTHR, 8) void pose_loss_fused_kernel(
    const float4* __restrict__ pred, const float4* __restrict__ gt,
    const int* __restrict__ Ms, float* __restrict__ out,
    int* __restrict__ counter, float* __restrict__ partials /* 4 floats/block */)
{
    const int cum0 = Ms[0];
    const int cum1 = cum0 + Ms[1];
    const int cum2 = cum1 + Ms[2];

    float all_t = 0.f, all_s = 0.f, intra_t = 0.f, intra_s = 0.f;

    auto body = [&](int idx) {
        const float4 p = pred[idx];
        const float4 g = gt[idx];
        const float d0 = p.x - g.x;
        const float d1 = p.y - g.y;
        const float d2 = p.z - g.z;
        const float d3 = p.w - g.w;
        const float t = d0 * d0 + d1 * d1;
        const float s = d2 * d2 + d3 * d3;
        all_t += t;
        all_s += s;
        const int q = idx / M_;          // magic-mul div (M_ constexpr)
        const int j = idx - q * M_;
        const int i = q - (q / M_) * M_;
        const int vi = (i >= cum0) + (i >= cum1) + (i >= cum2);
        const int vj = (j >= cum0) + (j >= cum1) + (j >= cum2);
        if (vi == vj) { intra_t += t; intra_s += s; }
    };

    int idx = blockIdx.x * PER_BLOCK + threadIdx.x;
    #pragma unroll 2
    for (int k = 0; k < KFULL; ++k, idx += NTHR) body(idx);
    if (threadIdx.x < TAILN) body(idx);

    // Wave (64-lane) shuffle reduction, then LDS across the 4 waves.
    float v0 = all_t, v1 = all_s, v2 = intra_t, v3 = intra_s;
    #pragma unroll
    for (int off = 32; off > 0; off >>= 1) {
        v0 += __shfl_down(v0, off, 64);
        v1 += __shfl_down(v1, off, 64);
        v2 += __shfl_down(v2, off, 64);
        v3 += __shfl_down(v3, off, 64);
    }

    __shared__ float4 sm[NTHR / 64];
    __shared__ int slast;
    const int lane = threadIdx.x & 63;
    const int wid  = threadIdx.x >> 6;
    if (lane == 0) sm[wid] = make_float4(v0, v1, v2, v3);
    __syncthreads();

    if (threadIdx.x == 0) {
        float4 acc = sm[0];
        #pragma unroll
        for (int w = 1; w < NTHR / 64; ++w) {
            acc.x += sm[w].x; acc.y += sm[w].y;
            acc.z += sm[w].z; acc.w += sm[w].w;
        }
        // Publish partial with agent-scope stores, then release via the
        // acq_rel atomic increment (standard threadfence-reduction pattern,
        // made XCD-coherence-safe with explicit agent scope).
        float* pp = partials + (size_t)blockIdx.x * 4;
        __hip_atomic_store(pp + 0, acc.x, __ATOMIC_RELAXED, __HIP_MEMORY_SCOPE_AGENT);
        __hip_atomic_store(pp + 1, acc.y, __ATOMIC_RELAXED, __HIP_MEMORY_SCOPE_AGENT);
        __hip_atomic_store(pp + 2, acc.z, __ATOMIC_RELAXED, __HIP_MEMORY_SCOPE_AGENT);
        __hip_atomic_store(pp + 3, acc.w, __ATOMIC_RELAXED, __HIP_MEMORY_SCOPE_AGENT);
        const int prev = __hip_atomic_fetch_add(counter, 1, __ATOMIC_ACQ_REL,
                                                __HIP_MEMORY_SCOPE_AGENT);
        slast = (prev == NBLK - 1) ? 1 : 0;
    }
    __syncthreads();
    if (slast == 0) return;

    // Last block: deterministic fixed-order reduction of all partials.
    float r0 = 0.f, r1 = 0.f, r2 = 0.f, r3 = 0.f;
    for (int p = threadIdx.x; p < NBLK; p += NTHR) {
        const float* pp = partials + (size_t)p * 4;
        r0 += __hip_atomic_load(pp + 0, __ATOMIC_RELAXED, __HIP_MEMORY_SCOPE_AGENT);
        r1 += __hip_atomic_load(pp + 1, __ATOMIC_RELAXED, __HIP_MEMORY_SCOPE_AGENT);
        r2 += __hip_atomic_load(pp + 2, __ATOMIC_RELAXED, __HIP_MEMORY_SCOPE_AGENT);
        r3 += __hip_atomic_load(pp + 3, __ATOMIC_RELAXED, __HIP_MEMORY_SCOPE_AGENT);
    }
    #pragma unroll
    for (int off = 32; off > 0; off >>= 1) {
        r0 += __shfl_down(r0, off, 64);
        r1 += __shfl_down(r1, off, 64);
        r2 += __shfl_down(r2, off, 64);
        r3 += __shfl_down(r3, off, 64);
    }
    if (lane == 0) sm[wid] = make_float4(r0, r1, r2, r3);
    __syncthreads();

    if (threadIdx.x == 0) {
        float4 acc = sm[0];
        #pragma unroll
        for (int w = 1; w < NTHR / 64; ++w) {
            acc.x += sm[w].x; acc.y += sm[w].y;
            acc.z += sm[w].z; acc.w += sm[w].w;
        }
        final_math(acc.x, acc.y, acc.z, acc.w, Ms, out);
    }
}

// ---------------------------------------------------------------------------
// Fallback two-kernel path (used only if ws_size is unexpectedly tight).
// ---------------------------------------------------------------------------
__global__ __launch_bounds__(NTHR) void pose_loss_partial_kernel(
    const float4* __restrict__ pred, const float4* __restrict__ gt,
    const int* __restrict__ Ms, float4* __restrict__ partials)
{
    const int cum0 = Ms[0];
    const int cum1 = cum0 + Ms[1];
    const int cum2 = cum1 + Ms[2];

    float all_t = 0.f, all_s = 0.f, intra_t = 0.f, intra_s = 0.f;
    for (int idx = blockIdx.x * NTHR + threadIdx.x; idx < TOTAL;
         idx += gridDim.x * NTHR) {
        const float4 p = pred[idx];
        const float4 g = gt[idx];
        const float d0 = p.x - g.x;
        const float d1 = p.y - g.y;
        const float d2 = p.z - g.z;
        const float d3 = p.w - g.w;
        const float t = d0 * d0 + d1 * d1;
        const float s = d2 * d2 + d3 * d3;
        all_t += t; all_s += s;
        const int q = idx / M_;
        const int j = idx - q * M_;
        const int i = q - (q / M_) * M_;
        const int vi = (i >= cum0) + (i >= cum1) + (i >= cum2);
        const int vj = (j >= cum0) + (j >= cum1) + (j >= cum2);
        if (vi == vj) { intra_t += t; intra_s += s; }
    }

    float v0 = all_t, v1 = all_s, v2 = intra_t, v3 = intra_s;
    #pragma unroll
    for (int off = 32; off > 0; off >>= 1) {
        v0 += __shfl_down(v0, off, 64);
        v1 += __shfl_down(v1, off, 64);
        v2 += __shfl_down(v2, off, 64);
        v3 += __shfl_down(v3, off, 64);
    }
    __shared__ float4 sm[NTHR / 64];
    const int lane = threadIdx.x & 63;
    const int wid  = threadIdx.x >> 6;
    if (lane == 0) sm[wid] = make_float4(v0, v1, v2, v3);
    __syncthreads();
    if (threadIdx.x == 0) {
        float4 acc = sm[0];
        #pragma unroll
        for (int w = 1; w < NTHR / 64; ++w) {
            acc.x += sm[w].x; acc.y += sm[w].y;
            acc.z += sm[w].z; acc.w += sm[w].w;
        }
        partials[blockIdx.x] = acc;
    }
}

__global__ __launch_bounds__(NTHR) void pose_loss_final_kernel(
    const float4* __restrict__ partials, int nprt, const int* __restrict__ Ms,
    float* __restrict__ out)
{
    float v0 = 0.f, v1 = 0.f, v2 = 0.f, v3 = 0.f;
    for (int p = threadIdx.x; p < nprt; p += NTHR) {
        const float4 q = partials[p];
        v0 += q.x; v1 += q.y; v2 += q.z; v3 += q.w;
    }
    #pragma unroll
    for (int off = 32; off > 0; off >>= 1) {
        v0 += __shfl_down(v0, off, 64);
        v1 += __shfl_down(v1, off, 64);
        v2 += __shfl_down(v2, off, 64);
        v3 += __shfl_down(v3, off, 64);
    }
    __shared__ float4 sm[NTHR / 64];
    const int lane = threadIdx.x & 63;
    const int wid  = threadIdx.x >> 6;
    if (lane == 0) sm[wid] = make_float4(v0, v1, v2, v3);
    __syncthreads();
    if (threadIdx.x == 0) {
        float4 acc = sm[0];
        #pragma unroll
        for (int w = 1; w < NTHR / 64; ++w) {
            acc.x += sm[w].x; acc.y += sm[w].y;
            acc.z += sm[w].z; acc.w += sm[w].w;
        }
        final_math(acc.x, acc.y, acc.z, acc.w, Ms, out);
    }
}

extern "C" void kernel_launch(void* const* d_in, const int* in_sizes, int n_in,
                              void* d_out, int out_size, void* d_ws, size_t ws_size,
                              hipStream_t stream) {
    const float4* pred = (const float4*)d_in[0];
    const float4* gt   = (const float4*)d_in[1];
    const int*    Ms   = (const int*)d_in[2];
    float*        out  = (float*)d_out;

    const size_t fused_need = 16 + (size_t)NBLK * 16;  // counter pad + partials
    if (ws_size >= fused_need) {
        int*   counter  = (int*)d_ws;
        float* partials = (float*)((char*)d_ws + 16);
        hipMemsetAsync(d_ws, 0, 16, stream);  // reset counter (capture-legal)
        pose_loss_fused_kernel<<<NBLK, NTHR, 0, stream>>>(pred, gt, Ms, out,
                                                          counter, partials);
    } else {
        const int nblk = 1792;
        float4* partials = (float4*)d_ws;
        pose_loss_partial_kernel<<<nblk, NTHR, 0, stream>>>(pred, gt, Ms, partials);
        pose_loss_final_kernel<<<1, NTHR, 0, stream>>>(partials, nblk, Ms, out);
    }
}

// Round 4
// 201.545 us; speedup vs baseline: 1.0792x; 1.0792x over previous
//
#include <hip/hip_runtime.h>

// Problem constants (fixed by setup_inputs in the reference):
//   pred_dT, gt_dT: (B=32, M=784, M=784, C=4) float32
//   Ms: (V=4,) int32, sum(Ms) == M
constexpr int B_ = 32;
constexpr int M_ = 784;

constexpr int NBLK = 1792;             // proven R2 config: flat stride sweep
constexpr int NTHR = 256;
constexpr int TOTAL  = B_ * M_ * M_;   // 19,668,992 float4 pixels per tensor
constexpr int STRIDE = NBLK * NTHR;    // 458,752
constexpr int KFULL  = TOTAL / STRIDE; // 42 full iterations + 87.5% tail

constexpr float ALPHA_T  = 0.5f;
constexpr float ALPHA_S  = 0.75f;
constexpr float ALPHA_TS = 0.5f;
constexpr float EPS      = 1e-8f;

__device__ __forceinline__ void final_math(float total_all_t, float total_all_s,
                                           float total_intra_t, float total_intra_s,
                                           const int* __restrict__ Ms,
                                           float* __restrict__ out)
{
    const float total_inter_t = total_all_t - total_intra_t;
    const float total_inter_s = total_all_s - total_intra_s;

    int sum_Ms_sq = 0;
    #pragma unroll
    for (int v = 0; v < 4; ++v) sum_Ms_sq += Ms[v] * Ms[v];
    const float diag_count    = (float)((long long)sum_Ms_sq * B_);
    const float offdiag_count = (float)(((long long)M_ * M_ - sum_Ms_sq) * B_);

    const float li_t = (diag_count    > EPS) ? total_intra_t / diag_count    : 0.f;
    const float le_t = (offdiag_count > EPS) ? total_inter_t / offdiag_count : 0.f;
    const float li_s = (diag_count    > EPS) ? total_intra_s / diag_count    : 0.f;
    const float le_s = (offdiag_count > EPS) ? total_inter_s / offdiag_count : 0.f;

    const float loss_t = ALPHA_T  * le_t + (1.f - ALPHA_T)  * li_t;
    const float loss_s = ALPHA_S  * le_s + (1.f - ALPHA_S)  * li_s;
    const float loss   = ALPHA_TS * loss_t + (1.f - ALPHA_TS) * loss_s;

    out[0] = li_t;
    out[1] = le_t;
    out[2] = li_s;
    out[3] = le_s;
    out[4] = loss_t;
    out[5] = loss_s;
    out[6] = loss;
}

// ---------------------------------------------------------------------------
// Fused kernel, R2 memory pattern: flat grid-stride sweep (all blocks march
// through one contiguous ~7MB window at a time -> DRAM row locality).
// Finish: per-block partial publish + agent-scope counter; the last block
// does a deterministic fixed-order reduction and the scalar epilogue.
// ---------------------------------------------------------------------------
__global__ __launch_bounds__(NTHR) void pose_loss_fused_kernel(
    const float4* __restrict__ pred, const float4* __restrict__ gt,
    const int* __restrict__ Ms, float* __restrict__ out,
    int* __restrict__ counter, float* __restrict__ partials /* 4 floats/block */)
{
    const int cum0 = Ms[0];
    const int cum1 = cum0 + Ms[1];
    const int cum2 = cum1 + Ms[2];

    float all_t = 0.f, all_s = 0.f, intra_t = 0.f, intra_s = 0.f;

    auto body = [&](int idx) {
        const float4 p = pred[idx];
        const float4 g = gt[idx];
        const float d0 = p.x - g.x;
        const float d1 = p.y - g.y;
        const float d2 = p.z - g.z;
        const float d3 = p.w - g.w;
        const float t = d0 * d0 + d1 * d1;
        const float s = d2 * d2 + d3 * d3;
        all_t += t;
        all_s += s;
        const int q = idx / M_;          // magic-mul div (M_ constexpr)
        const int j = idx - q * M_;
        const int i = q - (q / M_) * M_;
        const int vi = (i >= cum0) + (i >= cum1) + (i >= cum2);
        const int vj = (j >= cum0) + (j >= cum1) + (j >= cum2);
        if (vi == vj) { intra_t += t; intra_s += s; }
    };

    int idx = blockIdx.x * NTHR + threadIdx.x;
    #pragma unroll 2
    for (int k = 0; k < KFULL; ++k, idx += STRIDE) body(idx);
    if (idx < TOTAL) body(idx);    // single 87.5%-active tail iteration

    // Wave (64-lane) shuffle reduction, then LDS across the 4 waves.
    float v0 = all_t, v1 = all_s, v2 = intra_t, v3 = intra_s;
    #pragma unroll
    for (int off = 32; off > 0; off >>= 1) {
        v0 += __shfl_down(v0, off, 64);
        v1 += __shfl_down(v1, off, 64);
        v2 += __shfl_down(v2, off, 64);
        v3 += __shfl_down(v3, off, 64);
    }

    __shared__ float4 sm[NTHR / 64];
    __shared__ int slast;
    const int lane = threadIdx.x & 63;
    const int wid  = threadIdx.x >> 6;
    if (lane == 0) sm[wid] = make_float4(v0, v1, v2, v3);
    __syncthreads();

    if (threadIdx.x == 0) {
        float4 acc = sm[0];
        #pragma unroll
        for (int w = 1; w < NTHR / 64; ++w) {
            acc.x += sm[w].x; acc.y += sm[w].y;
            acc.z += sm[w].z; acc.w += sm[w].w;
        }
        float* pp = partials + (size_t)blockIdx.x * 4;
        __hip_atomic_store(pp + 0, acc.x, __ATOMIC_RELAXED, __HIP_MEMORY_SCOPE_AGENT);
        __hip_atomic_store(pp + 1, acc.y, __ATOMIC_RELAXED, __HIP_MEMORY_SCOPE_AGENT);
        __hip_atomic_store(pp + 2, acc.z, __ATOMIC_RELAXED, __HIP_MEMORY_SCOPE_AGENT);
        __hip_atomic_store(pp + 3, acc.w, __ATOMIC_RELAXED, __HIP_MEMORY_SCOPE_AGENT);
        const int prev = __hip_atomic_fetch_add(counter, 1, __ATOMIC_ACQ_REL,
                                                __HIP_MEMORY_SCOPE_AGENT);
        slast = (prev == NBLK - 1) ? 1 : 0;
    }
    __syncthreads();
    if (slast == 0) return;

    // Last block: deterministic fixed-order reduction of all partials.
    float r0 = 0.f, r1 = 0.f, r2 = 0.f, r3 = 0.f;
    for (int p = threadIdx.x; p < NBLK; p += NTHR) {
        const float* pp = partials + (size_t)p * 4;
        r0 += __hip_atomic_load(pp + 0, __ATOMIC_RELAXED, __HIP_MEMORY_SCOPE_AGENT);
        r1 += __hip_atomic_load(pp + 1, __ATOMIC_RELAXED, __HIP_MEMORY_SCOPE_AGENT);
        r2 += __hip_atomic_load(pp + 2, __ATOMIC_RELAXED, __HIP_MEMORY_SCOPE_AGENT);
        r3 += __hip_atomic_load(pp + 3, __ATOMIC_RELAXED, __HIP_MEMORY_SCOPE_AGENT);
    }
    #pragma unroll
    for (int off = 32; off > 0; off >>= 1) {
        r0 += __shfl_down(r0, off, 64);
        r1 += __shfl_down(r1, off, 64);
        r2 += __shfl_down(r2, off, 64);
        r3 += __shfl_down(r3, off, 64);
    }
    if (lane == 0) sm[wid] = make_float4(r0, r1, r2, r3);
    __syncthreads();

    if (threadIdx.x == 0) {
        float4 acc = sm[0];
        #pragma unroll
        for (int w = 1; w < NTHR / 64; ++w) {
            acc.x += sm[w].x; acc.y += sm[w].y;
            acc.z += sm[w].z; acc.w += sm[w].w;
        }
        final_math(acc.x, acc.y, acc.z, acc.w, Ms, out);
    }
}

// ---------------------------------------------------------------------------
// Fallback two-kernel path (used only if ws_size is unexpectedly tight).
// ---------------------------------------------------------------------------
__global__ __launch_bounds__(NTHR) void pose_loss_partial_kernel(
    const float4* __restrict__ pred, const float4* __restrict__ gt,
    const int* __restrict__ Ms, float4* __restrict__ partials)
{
    const int cum0 = Ms[0];
    const int cum1 = cum0 + Ms[1];
    const int cum2 = cum1 + Ms[2];

    float all_t = 0.f, all_s = 0.f, intra_t = 0.f, intra_s = 0.f;
    for (int idx = blockIdx.x * NTHR + threadIdx.x; idx < TOTAL;
         idx += gridDim.x * NTHR) {
        const float4 p = pred[idx];
        const float4 g = gt[idx];
        const float d0 = p.x - g.x;
        const float d1 = p.y - g.y;
        const float d2 = p.z - g.z;
        const float d3 = p.w - g.w;
        const float t = d0 * d0 + d1 * d1;
        const float s = d2 * d2 + d3 * d3;
        all_t += t; all_s += s;
        const int q = idx / M_;
        const int j = idx - q * M_;
        const int i = q - (q / M_) * M_;
        const int vi = (i >= cum0) + (i >= cum1) + (i >= cum2);
        const int vj = (j >= cum0) + (j >= cum1) + (j >= cum2);
        if (vi == vj) { intra_t += t; intra_s += s; }
    }

    float v0 = all_t, v1 = all_s, v2 = intra_t, v3 = intra_s;
    #pragma unroll
    for (int off = 32; off > 0; off >>= 1) {
        v0 += __shfl_down(v0, off, 64);
        v1 += __shfl_down(v1, off, 64);
        v2 += __shfl_down(v2, off, 64);
        v3 += __shfl_down(v3, off, 64);
    }
    __shared__ float4 sm[NTHR / 64];
    const int lane = threadIdx.x & 63;
    const int wid  = threadIdx.x >> 6;
    if (lane == 0) sm[wid] = make_float4(v0, v1, v2, v3);
    __syncthreads();
    if (threadIdx.x == 0) {
        float4 acc = sm[0];
        #pragma unroll
        for (int w = 1; w < NTHR / 64; ++w) {
            acc.x += sm[w].x; acc.y += sm[w].y;
            acc.z += sm[w].z; acc.w += sm[w].w;
        }
        partials[blockIdx.x] = acc;
    }
}

__global__ __launch_bounds__(NTHR) void pose_loss_final_kernel(
    const float4* __restrict__ partials, int nprt, const int* __restrict__ Ms,
    float* __restrict__ out)
{
    float v0 = 0.f, v1 = 0.f, v2 = 0.f, v3 = 0.f;
    for (int p = threadIdx.x; p < nprt; p += NTHR) {
        const float4 q = partials[p];
        v0 += q.x; v1 += q.y; v2 += q.z; v3 += q.w;
    }
    #pragma unroll
    for (int off = 32; off > 0; off >>= 1) {
        v0 += __shfl_down(v0, off, 64);
        v1 += __shfl_down(v1, off, 64);
        v2 += __shfl_down(v2, off, 64);
        v3 += __shfl_down(v3, off, 64);
    }
    __shared__ float4 sm[NTHR / 64];
    const int lane = threadIdx.x & 63;
    const int wid  = threadIdx.x >> 6;
    if (lane == 0) sm[wid] = make_float4(v0, v1, v2, v3);
    __syncthreads();
    if (threadIdx.x == 0) {
        float4 acc = sm[0];
        #pragma unroll
        for (int w = 1; w < NTHR / 64; ++w) {
            acc.x += sm[w].x; acc.y += sm[w].y;
            acc.z += sm[w].z; acc.w += sm[w].w;
        }
        final_math(acc.x, acc.y, acc.z, acc.w, Ms, out);
    }
}

extern "C" void kernel_launch(void* const* d_in, const int* in_sizes, int n_in,
                              void* d_out, int out_size, void* d_ws, size_t ws_size,
                              hipStream_t stream) {
    const float4* pred = (const float4*)d_in[0];
    const float4* gt   = (const float4*)d_in[1];
    const int*    Ms   = (const int*)d_in[2];
    float*        out  = (float*)d_out;

    const size_t fused_need = 16 + (size_t)NBLK * 16;  // counter pad + partials
    if (ws_size >= fused_need) {
        int*   counter  = (int*)d_ws;
        float* partials = (float*)((char*)d_ws + 16);
        hipMemsetAsync(d_ws, 0, 16, stream);  // reset counter (capture-legal)
        pose_loss_fused_kernel<<<NBLK, NTHR, 0, stream>>>(pred, gt, Ms, out,
                                                          counter, partials);
    } else {
        float4* partials = (float4*)d_ws;
        pose_loss_partial_kernel<<<NBLK, NTHR, 0, stream>>>(pred, gt, Ms, partials);
        pose_loss_final_kernel<<<1, NTHR, 0, stream>>>(partials, NBLK, Ms, out);
    }
}

// Round 5
// 116.322 us; speedup vs baseline: 1.8698x; 1.7326x over previous
//
#include <hip/hip_runtime.h>

// Problem constants (fixed by setup_inputs in the reference):
//   pred_dT, gt_dT: (B=32, M=784, M=784, C=4) float32
//   Ms: (V=4,) int32, sum(Ms) == M
constexpr int B_ = 32;
constexpr int M_ = 784;

constexpr int NBLK = 1792;             // proven R2 config: flat stride sweep
constexpr int NTHR = 256;
constexpr int TOTAL  = B_ * M_ * M_;   // 19,668,992 float4 pixels per tensor
constexpr int STRIDE = NBLK * NTHR;    // 458,752
constexpr int KFULL  = TOTAL / STRIDE; // 42 full iterations + 87.5% tail

constexpr float ALPHA_T  = 0.5f;
constexpr float ALPHA_S  = 0.75f;
constexpr float ALPHA_TS = 0.5f;
constexpr float EPS      = 1e-8f;

// NOTE (R3/R4 lesson): fusing the final reduce via per-block agent-scope
// acq_rel atomics collapsed HBM BW to 1.2 TB/s (L2 writeback/invalidate
// storms from 1792 block-retirement fences). Two plain dispatches are ~2x
// faster overall. Do not re-fuse with device-scope atomics.

__device__ __forceinline__ void final_math(float total_all_t, float total_all_s,
                                           float total_intra_t, float total_intra_s,
                                           const int* __restrict__ Ms,
                                           float* __restrict__ out)
{
    const float total_inter_t = total_all_t - total_intra_t;
    const float total_inter_s = total_all_s - total_intra_s;

    int sum_Ms_sq = 0;
    #pragma unroll
    for (int v = 0; v < 4; ++v) sum_Ms_sq += Ms[v] * Ms[v];
    const float diag_count    = (float)((long long)sum_Ms_sq * B_);
    const float offdiag_count = (float)(((long long)M_ * M_ - sum_Ms_sq) * B_);

    const float li_t = (diag_count    > EPS) ? total_intra_t / diag_count    : 0.f;
    const float le_t = (offdiag_count > EPS) ? total_inter_t / offdiag_count : 0.f;
    const float li_s = (diag_count    > EPS) ? total_intra_s / diag_count    : 0.f;
    const float le_s = (offdiag_count > EPS) ? total_inter_s / offdiag_count : 0.f;

    const float loss_t = ALPHA_T  * le_t + (1.f - ALPHA_T)  * li_t;
    const float loss_s = ALPHA_S  * le_s + (1.f - ALPHA_S)  * li_s;
    const float loss   = ALPHA_TS * loss_t + (1.f - ALPHA_TS) * loss_s;

    out[0] = li_t;
    out[1] = le_t;
    out[2] = li_s;
    out[3] = le_s;
    out[4] = loss_t;
    out[5] = loss_s;
    out[6] = loss;
}

// ---------------------------------------------------------------------------
// Kernel 1: flat grid-stride over all (b,i,j) pixels. One float4 per tensor
// per thread-iteration (C=4 channels contiguous). Accumulate 4 sums:
// all_t, all_s, intra_t, intra_s (intra := view(i)==view(j)).
// One float4 partial per block -> d_ws. No atomics anywhere.
// ---------------------------------------------------------------------------
__global__ __launch_bounds__(NTHR) void pose_loss_partial_kernel(
    const float4* __restrict__ pred, const float4* __restrict__ gt,
    const int* __restrict__ Ms, float4* __restrict__ partials)
{
    const int cum0 = Ms[0];
    const int cum1 = cum0 + Ms[1];
    const int cum2 = cum1 + Ms[2];

    float all_t = 0.f, all_s = 0.f, intra_t = 0.f, intra_s = 0.f;

    auto body = [&](int idx) {
        const float4 p = pred[idx];
        const float4 g = gt[idx];
        const float d0 = p.x - g.x;
        const float d1 = p.y - g.y;
        const float d2 = p.z - g.z;
        const float d3 = p.w - g.w;
        const float t = d0 * d0 + d1 * d1;
        const float s = d2 * d2 + d3 * d3;
        all_t += t;
        all_s += s;
        const int q = idx / M_;        // magic-mul div (M_ constexpr)
        const int j = idx - q * M_;
        const int i = q - (q / M_) * M_;
        const int vi = (i >= cum0) + (i >= cum1) + (i >= cum2);
        const int vj = (j >= cum0) + (j >= cum1) + (j >= cum2);
        if (vi == vj) { intra_t += t; intra_s += s; }
    };

    int idx = blockIdx.x * NTHR + threadIdx.x;
    #pragma unroll 4
    for (int k = 0; k < KFULL; ++k, idx += STRIDE) {
        body(idx);
    }
    if (idx < TOTAL) {   // single 87.5%-active tail iteration
        body(idx);
    }

    // Wave (64-lane) shuffle reduction, then LDS across the 4 waves.
    float v0 = all_t, v1 = all_s, v2 = intra_t, v3 = intra_s;
    #pragma unroll
    for (int off = 32; off > 0; off >>= 1) {
        v0 += __shfl_down(v0, off, 64);
        v1 += __shfl_down(v1, off, 64);
        v2 += __shfl_down(v2, off, 64);
        v3 += __shfl_down(v3, off, 64);
    }

    __shared__ float4 sm[NTHR / 64];
    const int lane = threadIdx.x & 63;
    const int wid  = threadIdx.x >> 6;
    if (lane == 0) sm[wid] = make_float4(v0, v1, v2, v3);
    __syncthreads();

    if (threadIdx.x == 0) {
        float4 acc = sm[0];
        #pragma unroll
        for (int w = 1; w < NTHR / 64; ++w) {
            acc.x += sm[w].x; acc.y += sm[w].y;
            acc.z += sm[w].z; acc.w += sm[w].w;
        }
        partials[blockIdx.x] = acc;
    }
}

// ---------------------------------------------------------------------------
// Kernel 2: single block. Deterministic reduction of NBLK partials, then the
// scalar loss arithmetic, writing the 7-element output vector.
// ---------------------------------------------------------------------------
__global__ __launch_bounds__(NTHR) void pose_loss_final_kernel(
    const float4* __restrict__ partials, const int* __restrict__ Ms,
    float* __restrict__ out)
{
    float v0 = 0.f, v1 = 0.f, v2 = 0.f, v3 = 0.f;
    for (int p = threadIdx.x; p < NBLK; p += NTHR) {
        const float4 q = partials[p];
        v0 += q.x; v1 += q.y; v2 += q.z; v3 += q.w;
    }
    #pragma unroll
    for (int off = 32; off > 0; off >>= 1) {
        v0 += __shfl_down(v0, off, 64);
        v1 += __shfl_down(v1, off, 64);
        v2 += __shfl_down(v2, off, 64);
        v3 += __shfl_down(v3, off, 64);
    }
    __shared__ float4 sm[NTHR / 64];
    const int lane = threadIdx.x & 63;
    const int wid  = threadIdx.x >> 6;
    if (lane == 0) sm[wid] = make_float4(v0, v1, v2, v3);
    __syncthreads();

    if (threadIdx.x == 0) {
        float4 acc = sm[0];
        #pragma unroll
        for (int w = 1; w < NTHR / 64; ++w) {
            acc.x += sm[w].x; acc.y += sm[w].y;
            acc.z += sm[w].z; acc.w += sm[w].w;
        }
        final_math(acc.x, acc.y, acc.z, acc.w, Ms, out);
    }
}

extern "C" void kernel_launch(void* const* d_in, const int* in_sizes, int n_in,
                              void* d_out, int out_size, void* d_ws, size_t ws_size,
                              hipStream_t stream) {
    const float4* pred = (const float4*)d_in[0];
    const float4* gt   = (const float4*)d_in[1];
    const int*    Ms   = (const int*)d_in[2];
    float*        out  = (float*)d_out;
    float4*       partials = (float4*)d_ws;   // NBLK * 16 bytes = 28 KB

    pose_loss_partial_kernel<<<NBLK, NTHR, 0, stream>>>(pred, gt, Ms, partials);
    pose_loss_final_kernel<<<1, NTHR, 0, stream>>>(partials, Ms, out);
}

// Round 6
// 101.578 us; speedup vs baseline: 2.1412x; 1.1452x over previous
//
#include <hip/hip_runtime.h>

// Problem constants (fixed by setup_inputs in the reference):
//   pred_dT, gt_dT: (B=32, M=784, M=784, C=4) float32
//   Ms: (V=4,) int32, sum(Ms) == M
constexpr int B_ = 32;
constexpr int M_ = 784;

constexpr int NBLK = 1792;             // proven R2 config: flat stride sweep
constexpr int NTHR = 256;
constexpr int TOTAL  = B_ * M_ * M_;   // 19,668,992 float4 pixels per tensor
constexpr int STRIDE = NBLK * NTHR;    // 458,752
constexpr int KFULL  = TOTAL / STRIDE; // 42 full iterations + 87.5% tail

constexpr float ALPHA_T  = 0.5f;
constexpr float ALPHA_S  = 0.75f;
constexpr float ALPHA_TS = 0.5f;
constexpr float EPS      = 1e-8f;

// NOTE (R3/R4 lesson): fusing the final reduce via per-block agent-scope
// acq_rel atomics collapsed HBM BW to 1.2 TB/s. Two plain dispatches win.
// NOTE (R5 lesson): unroll 4 is not better than unroll 2 (116.3 vs 113.0).

typedef float f32x4 __attribute__((ext_vector_type(4)));  // layout == float4

__device__ __forceinline__ void final_math(float total_all_t, float total_all_s,
                                           float total_intra_t, float total_intra_s,
                                           const int* __restrict__ Ms,
                                           float* __restrict__ out)
{
    const float total_inter_t = total_all_t - total_intra_t;
    const float total_inter_s = total_all_s - total_intra_s;

    int sum_Ms_sq = 0;
    #pragma unroll
    for (int v = 0; v < 4; ++v) sum_Ms_sq += Ms[v] * Ms[v];
    const float diag_count    = (float)((long long)sum_Ms_sq * B_);
    const float offdiag_count = (float)(((long long)M_ * M_ - sum_Ms_sq) * B_);

    const float li_t = (diag_count    > EPS) ? total_intra_t / diag_count    : 0.f;
    const float le_t = (offdiag_count > EPS) ? total_inter_t / offdiag_count : 0.f;
    const float li_s = (diag_count    > EPS) ? total_intra_s / diag_count    : 0.f;
    const float le_s = (offdiag_count > EPS) ? total_inter_s / offdiag_count : 0.f;

    const float loss_t = ALPHA_T  * le_t + (1.f - ALPHA_T)  * li_t;
    const float loss_s = ALPHA_S  * le_s + (1.f - ALPHA_S)  * li_s;
    const float loss   = ALPHA_TS * loss_t + (1.f - ALPHA_TS) * loss_s;

    out[0] = li_t;
    out[1] = le_t;
    out[2] = li_s;
    out[3] = le_s;
    out[4] = loss_t;
    out[5] = loss_s;
    out[6] = loss;
}

// ---------------------------------------------------------------------------
// Kernel 1: flat grid-stride over all (b,i,j) pixels. One float4 per tensor
// per thread-iteration, loaded NON-TEMPORALLY (pure one-pass stream, zero
// reuse -> let TCC evict early instead of thrashing L2/L3).
// One float4 partial per block -> d_ws. No atomics anywhere.
// ---------------------------------------------------------------------------
__global__ __launch_bounds__(NTHR) void pose_loss_partial_kernel(
    const f32x4* __restrict__ pred, const f32x4* __restrict__ gt,
    const int* __restrict__ Ms, float4* __restrict__ partials)
{
    const int cum0 = Ms[0];
    const int cum1 = cum0 + Ms[1];
    const int cum2 = cum1 + Ms[2];

    float all_t = 0.f, all_s = 0.f, intra_t = 0.f, intra_s = 0.f;

    auto body = [&](int idx) {
        const f32x4 p = __builtin_nontemporal_load(pred + idx);
        const f32x4 g = __builtin_nontemporal_load(gt + idx);
        const float d0 = p.x - g.x;
        const float d1 = p.y - g.y;
        const float d2 = p.z - g.z;
        const float d3 = p.w - g.w;
        const float t = d0 * d0 + d1 * d1;
        const float s = d2 * d2 + d3 * d3;
        all_t += t;
        all_s += s;
        const int q = idx / M_;        // magic-mul div (M_ constexpr)
        const int j = idx - q * M_;
        const int i = q - (q / M_) * M_;
        const int vi = (i >= cum0) + (i >= cum1) + (i >= cum2);
        const int vj = (j >= cum0) + (j >= cum1) + (j >= cum2);
        if (vi == vj) { intra_t += t; intra_s += s; }
    };

    int idx = blockIdx.x * NTHR + threadIdx.x;
    #pragma unroll 2
    for (int k = 0; k < KFULL; ++k, idx += STRIDE) {
        body(idx);
    }
    if (idx < TOTAL) {   // single 87.5%-active tail iteration
        body(idx);
    }

    // Wave (64-lane) shuffle reduction, then LDS across the 4 waves.
    float v0 = all_t, v1 = all_s, v2 = intra_t, v3 = intra_s;
    #pragma unroll
    for (int off = 32; off > 0; off >>= 1) {
        v0 += __shfl_down(v0, off, 64);
        v1 += __shfl_down(v1, off, 64);
        v2 += __shfl_down(v2, off, 64);
        v3 += __shfl_down(v3, off, 64);
    }

    __shared__ float4 sm[NTHR / 64];
    const int lane = threadIdx.x & 63;
    const int wid  = threadIdx.x >> 6;
    if (lane == 0) sm[wid] = make_float4(v0, v1, v2, v3);
    __syncthreads();

    if (threadIdx.x == 0) {
        float4 acc = sm[0];
        #pragma unroll
        for (int w = 1; w < NTHR / 64; ++w) {
            acc.x += sm[w].x; acc.y += sm[w].y;
            acc.z += sm[w].z; acc.w += sm[w].w;
        }
        partials[blockIdx.x] = acc;
    }
}

// ---------------------------------------------------------------------------
// Kernel 2: single block. Deterministic reduction of NBLK partials, then the
// scalar loss arithmetic, writing the 7-element output vector.
// ---------------------------------------------------------------------------
__global__ __launch_bounds__(NTHR) void pose_loss_final_kernel(
    const float4* __restrict__ partials, const int* __restrict__ Ms,
    float* __restrict__ out)
{
    float v0 = 0.f, v1 = 0.f, v2 = 0.f, v3 = 0.f;
    for (int p = threadIdx.x; p < NBLK; p += NTHR) {
        const float4 q = partials[p];
        v0 += q.x; v1 += q.y; v2 += q.z; v3 += q.w;
    }
    #pragma unroll
    for (int off = 32; off > 0; off >>= 1) {
        v0 += __shfl_down(v0, off, 64);
        v1 += __shfl_down(v1, off, 64);
        v2 += __shfl_down(v2, off, 64);
        v3 += __shfl_down(v3, off, 64);
    }
    __shared__ float4 sm[NTHR / 64];
    const int lane = threadIdx.x & 63;
    const int wid  = threadIdx.x >> 6;
    if (lane == 0) sm[wid] = make_float4(v0, v1, v2, v3);
    __syncthreads();

    if (threadIdx.x == 0) {
        float4 acc = sm[0];
        #pragma unroll
        for (int w = 1; w < NTHR / 64; ++w) {
            acc.x += sm[w].x; acc.y += sm[w].y;
            acc.z += sm[w].z; acc.w += sm[w].w;
        }
        final_math(acc.x, acc.y, acc.z, acc.w, Ms, out);
    }
}

extern "C" void kernel_launch(void* const* d_in, const int* in_sizes, int n_in,
                              void* d_out, int out_size, void* d_ws, size_t ws_size,
                              hipStream_t stream) {
    const f32x4* pred = (const f32x4*)d_in[0];
    const f32x4* gt   = (const f32x4*)d_in[1];
    const int*   Ms   = (const int*)d_in[2];
    float*       out  = (float*)d_out;
    float4*      partials = (float4*)d_ws;   // NBLK * 16 bytes = 28 KB

    pose_loss_partial_kernel<<<NBLK, NTHR, 0, stream>>>(pred, gt, Ms, partials);
    pose_loss_final_kernel<<<1, NTHR, 0, stream>>>(partials, Ms, out);
}